// Round 1
// baseline (1077.835 us; speedup 1.0000x reference)
//
#include <hip/hip_runtime.h>
#include <hip/hip_bf16.h>
#include <math.h>

typedef short v8s __attribute__((ext_vector_type(8)));
typedef float v4f __attribute__((ext_vector_type(4)));
typedef __hip_bfloat16 bf16;

__device__ inline short f2b(float f){
  __hip_bfloat16 h = __float2bfloat16(f);
  return __builtin_bit_cast(short, h);
}

__device__ inline v4f v4f_zero(){ v4f z = {0.f,0.f,0.f,0.f}; return z; }

__device__ inline void gload_lds16(const void* g, void* l){
  __builtin_amdgcn_global_load_lds(
      (__attribute__((address_space(1))) void*)(g),
      (__attribute__((address_space(3))) void*)(l), 16, 0, 0);
}

// ---------------- fp32 -> bf16 convert ----------------
__global__ __launch_bounds__(256) void k_cvt(const float* __restrict__ in,
                                             bf16* __restrict__ out, int n4){
  int i = blockIdx.x*256 + threadIdx.x;
  const int stride = gridDim.x*256;
  for (; i < n4; i += stride){
    float4 v = ((const float4*)in)[i];
    short4 o;
    o.x = f2b(v.x); o.y = f2b(v.y); o.z = f2b(v.z); o.w = f2b(v.w);
    ((short4*)out)[i] = o;
  }
}

// ---------------- LayerNorm: one wave per row of 512, fp32 in -> bf16 out ----------------
__global__ __launch_bounds__(256) void k_ln(const float* __restrict__ x,
                                            const float* __restrict__ w,
                                            const float* __restrict__ b,
                                            bf16* __restrict__ out){
  const int row  = blockIdx.x*4 + (threadIdx.x>>6);
  const int lane = threadIdx.x & 63;
  const float* xr = x + (size_t)row*512 + lane*8;
  float4 a = *(const float4*)xr;
  float4 c = *(const float4*)(xr+4);
  float s  = a.x+a.y+a.z+a.w + c.x+c.y+c.z+c.w;
  float sq = a.x*a.x+a.y*a.y+a.z*a.z+a.w*a.w + c.x*c.x+c.y*c.y+c.z*c.z+c.w*c.w;
  #pragma unroll
  for (int m=1;m<64;m<<=1){ s += __shfl_xor(s,m); sq += __shfl_xor(sq,m); }
  const float mean = s*(1.f/512.f);
  const float rstd = rsqrtf(sq*(1.f/512.f) - mean*mean + 1e-5f);
  const float* wp = w + lane*8; const float* bp = b + lane*8;
  float4 w0 = *(const float4*)wp, w1v = *(const float4*)(wp+4);
  float4 b0 = *(const float4*)bp, b1v = *(const float4*)(bp+4);
  v8s o;
  o[0]=f2b((a.x-mean)*rstd*w0.x +b0.x);
  o[1]=f2b((a.y-mean)*rstd*w0.y +b0.y);
  o[2]=f2b((a.z-mean)*rstd*w0.z +b0.z);
  o[3]=f2b((a.w-mean)*rstd*w0.w +b0.w);
  o[4]=f2b((c.x-mean)*rstd*w1v.x+b1v.x);
  o[5]=f2b((c.y-mean)*rstd*w1v.y+b1v.y);
  o[6]=f2b((c.z-mean)*rstd*w1v.z+b1v.z);
  o[7]=f2b((c.w-mean)*rstd*w1v.w+b1v.w);
  *(v8s*)(out + (size_t)row*512 + lane*8) = o;
}

// ---------------- GEMM: C[M,N] = A[M,K] * W[N,K]^T + bias, fused epilogues ----------------
enum { EPI_F32=0, EPI_BF16=1, EPI_F32RES=2, EPI_GELU=3 };

template<int BN, int EPI>
__global__ __launch_bounds__(256) void k_gemm(
    const bf16* __restrict__ A, const bf16* __restrict__ W,
    const float* __restrict__ bias,
    float* __restrict__ resf, bf16* __restrict__ outb,
    const int M, const int N, const int K)
{
  constexpr int BM = 128;
  constexpr int FN = BN/32;
  __shared__ __align__(16) bf16 As[2][BM*32];
  __shared__ __align__(16) bf16 Bs[2][BN*32];
  const int tid  = threadIdx.x;
  const int wave = tid>>6, lane = tid&63;
  const int r = lane&15, g = lane>>4;
  const int bm = blockIdx.x*BM, bn = blockIdx.y*BN;
  const int wr = wave>>1, wc = wave&1;

  v4f acc[4][FN];
  #pragma unroll
  for (int i=0;i<4;++i)
    #pragma unroll
    for (int j=0;j<FN;++j) acc[i][j] = v4f_zero();

  const int NT = K >> 5;

  auto stage = [&](int buf, int kb){
    #pragma unroll
    for (int it=0; it<BM/64; ++it){
      const int cb = it*256 + wave*64;
      const int cc = cb + lane;
      const bf16* gp = A + (size_t)(bm + (cc>>2))*K + kb + (cc&3)*8;
      gload_lds16(gp, &As[buf][cb*8]);
    }
    #pragma unroll
    for (int it=0; it<BN/64; ++it){
      const int cb = it*256 + wave*64;
      const int cc = cb + lane;
      const bf16* gp = W + (size_t)(bn + (cc>>2))*K + kb + (cc&3)*8;
      gload_lds16(gp, &Bs[buf][cb*8]);
    }
  };

  stage(0, 0);
  int cur = 0;
  for (int t=0; t<NT; ++t){
    __syncthreads();
    if (t+1 < NT) stage(cur^1, (t+1)*32);
    const bf16* ap = &As[cur][(wr*64 + r)*32 + g*8];
    const bf16* bp = &Bs[cur][(wc*(BN/2) + r)*32 + g*8];
    v8s af[4], bfr[FN];
    #pragma unroll
    for (int i=0;i<4;++i) af[i] = *(const v8s*)(ap + i*16*32);
    #pragma unroll
    for (int j=0;j<FN;++j) bfr[j] = *(const v8s*)(bp + j*16*32);
    #pragma unroll
    for (int i=0;i<4;++i)
      #pragma unroll
      for (int j=0;j<FN;++j)
        acc[i][j] = __builtin_amdgcn_mfma_f32_16x16x32_bf16(af[i], bfr[j], acc[i][j], 0,0,0);
    cur ^= 1;
  }

  #pragma unroll
  for (int j=0;j<FN;++j){
    const int col = bn + wc*(BN/2) + j*16 + r;
    const float bv = bias[col];
    #pragma unroll
    for (int i=0;i<4;++i){
      const int row0 = bm + wr*64 + i*16 + g*4;
      #pragma unroll
      for (int q=0;q<4;++q){
        float v = acc[i][j][q] + bv;
        const size_t idx = (size_t)(row0+q)*N + col;
        if constexpr (EPI==EPI_F32)         resf[idx] = v;
        else if constexpr (EPI==EPI_F32RES) resf[idx] += v;
        else if constexpr (EPI==EPI_BF16)   outb[idx] = __float2bfloat16(v);
        else {
          float gv = 0.5f*v*(1.f + erff(v*0.70710678118654752f));
          outb[idx] = __float2bfloat16(gv);
        }
      }
    }
  }
}

// ---------------- causal + ALiBi flash attention ----------------
// grid: (S/64, NH, B), block 256 (4 waves x 16 q-rows). hd=64, H=512, ld(qkv)=1536.
__global__ __launch_bounds__(256) void k_attn(const bf16* __restrict__ qkv,
                                              bf16* __restrict__ o){
  const int qb    = blockIdx.x*64;
  const int head  = blockIdx.y;
  const int batch = blockIdx.z;
  const int wave = threadIdx.x>>6, lane = threadIdx.x&63;
  const int r = lane&15, g = lane>>4;
  const float scale = 0.125f;                       // 1/sqrt(64)
  const float slope = exp2f(-(float)(head+1));      // ALiBi slopes for NH=8
  const bf16* qp = qkv + (size_t)batch*2048*1536 + head*64;
  const bf16* kp = qp + 512;
  const bf16* vp = qp + 1024;

  __shared__ __align__(16) bf16 Vs[32*64];
  __shared__ __align__(16) bf16 Ps[4][16*32];

  v8s qf0, qf1;
  {
    const bf16* qrow = qp + (size_t)(qb + wave*16 + r)*1536 + g*8;
    qf0 = *(const v8s*)qrow;
    qf1 = *(const v8s*)(qrow + 32);
  }

  v4f oacc[4];
  #pragma unroll
  for (int i=0;i<4;++i) oacc[i] = v4f_zero();
  float mj[4] = {-1e30f,-1e30f,-1e30f,-1e30f};
  float lj[4] = {0.f,0.f,0.f,0.f};

  const int ktiles = qb/32 + 2;
  for (int kt=0; kt<ktiles; ++kt){
    const int k0 = kt*32;
    __syncthreads();
    { // stage V tile [32 x 64] to LDS (linear, global_load_lds width 16)
      const int cc = wave*64 + lane;
      const bf16* gp = vp + (size_t)(k0 + (cc>>3))*1536 + (cc&7)*8;
      gload_lds16(gp, &Vs[wave*64*8]);
    }
    // scores: S[q, k] over 16q x 32k, K-frags straight from global (L2/L3-hot)
    v4f s0 = v4f_zero(), s1 = v4f_zero();
    {
      const bf16* kr = kp + (size_t)(k0 + r)*1536 + g*8;
      v8s k00 = *(const v8s*)(kr);
      v8s k10 = *(const v8s*)(kr + 32);
      v8s k01 = *(const v8s*)(kr + (size_t)16*1536);
      v8s k11 = *(const v8s*)(kr + (size_t)16*1536 + 32);
      s0 = __builtin_amdgcn_mfma_f32_16x16x32_bf16(qf0, k00, s0, 0,0,0);
      s0 = __builtin_amdgcn_mfma_f32_16x16x32_bf16(qf1, k10, s0, 0,0,0);
      s1 = __builtin_amdgcn_mfma_f32_16x16x32_bf16(qf0, k01, s1, 0,0,0);
      s1 = __builtin_amdgcn_mfma_f32_16x16x32_bf16(qf1, k11, s1, 0,0,0);
    }
    // online softmax (fp32), rows live across 16 lanes (same g, varying r)
    #pragma unroll
    for (int j=0;j<4;++j){
      const int q   = qb + wave*16 + g*4 + j;
      const int kc0 = k0 + r, kc1 = k0 + 16 + r;
      float v0 = (kc0<=q) ? s0[j]*scale - slope*(float)(q-kc0) : -1e30f;
      float v1 = (kc1<=q) ? s1[j]*scale - slope*(float)(q-kc1) : -1e30f;
      float mt = fmaxf(v0,v1);
      mt = fmaxf(mt, __shfl_xor(mt,1));
      mt = fmaxf(mt, __shfl_xor(mt,2));
      mt = fmaxf(mt, __shfl_xor(mt,4));
      mt = fmaxf(mt, __shfl_xor(mt,8));
      const float mnew  = fmaxf(mj[j], mt);
      const float alpha = __expf(mj[j]-mnew);
      const float p0 = __expf(v0-mnew);
      const float p1 = __expf(v1-mnew);
      float ps = p0+p1;
      ps += __shfl_xor(ps,1); ps += __shfl_xor(ps,2);
      ps += __shfl_xor(ps,4); ps += __shfl_xor(ps,8);
      lj[j] = lj[j]*alpha + ps;
      mj[j] = mnew;
      #pragma unroll
      for (int nf=0;nf<4;++nf) oacc[nf][j] *= alpha;
      Ps[wave][(g*4+j)*32 + r]      = __float2bfloat16(p0);
      Ps[wave][(g*4+j)*32 + r + 16] = __float2bfloat16(p1);
    }
    __syncthreads();   // V staged (drains vmcnt) + Ps ordered
    // PV: O[16q x 64d] += P[16q x 32k] * V[32k x 64d]
    v8s pf = *(const v8s*)&Ps[wave][r*32 + g*8];
    #pragma unroll
    for (int nf=0;nf<4;++nf){
      v8s vf;
      #pragma unroll
      for (int jj=0;jj<8;++jj)
        vf[jj] = __builtin_bit_cast(short, Vs[(g*8+jj)*64 + nf*16 + r]);
      oacc[nf] = __builtin_amdgcn_mfma_f32_16x16x32_bf16(pf, vf, oacc[nf], 0,0,0);
    }
  }

  #pragma unroll
  for (int j=0;j<4;++j){
    const int q = qb + wave*16 + g*4 + j;
    const float inv = 1.f/lj[j];
    bf16* orow = o + ((size_t)batch*2048 + q)*512 + head*64;
    #pragma unroll
    for (int nf=0;nf<4;++nf)
      orow[nf*16 + r] = __float2bfloat16(oacc[nf][j]*inv);
  }
}

// ---------------- orchestration ----------------
extern "C" void kernel_launch(void* const* d_in, const int* in_sizes, int n_in,
                              void* d_out, int out_size, void* d_ws, size_t ws_size,
                              hipStream_t stream)
{
  const float* x     = (const float*)d_in[0];
  const float* w_emb = (const float*)d_in[1];
  const float* b_emb = (const float*)d_in[2];
  const float* ln1_w = (const float*)d_in[3];
  const float* ln1_b = (const float*)d_in[4];
  const float* inp_w = (const float*)d_in[5];
  const float* inp_b = (const float*)d_in[6];
  const float* outp_w= (const float*)d_in[7];
  const float* outp_b= (const float*)d_in[8];
  const float* ln2_w = (const float*)d_in[9];
  const float* ln2_b = (const float*)d_in[10];
  const float* w1    = (const float*)d_in[11];
  const float* b1    = (const float*)d_in[12];
  const float* w2    = (const float*)d_in[13];
  const float* b2    = (const float*)d_in[14];
  const float* fln_w = (const float*)d_in[15];
  const float* fln_b = (const float*)d_in[16];
  const float* w_out = (const float*)d_in[17];
  const float* b_out = (const float*)d_in[18];

  char* wsp = (char*)d_ws;
  auto alloc = [&](size_t bytes){ void* p = (void*)wsp; wsp += (bytes + 255) & ~(size_t)255; return p; };
  float* h     = (float*)alloc(4096UL*512*4);
  bf16* xn     = (bf16*) alloc(4096UL*512*2);
  bf16* qkv    = (bf16*) alloc(4096UL*1536*2);
  bf16* ob     = (bf16*) alloc(4096UL*512*2);
  bf16* a1     = (bf16*) alloc(4096UL*2048*2);
  bf16* xbf    = (bf16*) alloc(4096UL*192*2);
  bf16* wembB  = (bf16*) alloc(512UL*192*2);
  bf16* inpwB  = (bf16*) alloc(4UL*1536*512*2);
  bf16* outpwB = (bf16*) alloc(4UL*512*512*2);
  bf16* w1B    = (bf16*) alloc(4UL*2048*512*2);
  bf16* w2B    = (bf16*) alloc(4UL*512*2048*2);
  bf16* woutB  = (bf16*) alloc(192UL*512*2);

  auto cvt = [&](const float* s, bf16* dst, size_t n){
    int n4 = (int)(n/4);
    int blocks = (n4 + 255)/256; if (blocks > 2048) blocks = 2048;
    k_cvt<<<dim3(blocks), dim3(256), 0, stream>>>(s, dst, n4);
  };
  cvt(x, xbf, 4096UL*192);
  cvt(w_emb, wembB, 512UL*192);
  cvt(inp_w, inpwB, 4UL*1536*512);
  cvt(outp_w, outpwB, 4UL*512*512);
  cvt(w1, w1B, 4UL*2048*512);
  cvt(w2, w2B, 4UL*512*2048);
  cvt(w_out, woutB, 192UL*512);

  // h = x @ w_emb.T + b_emb
  k_gemm<128, EPI_F32><<<dim3(32,4), 256, 0, stream>>>(xbf, wembB, b_emb, h, nullptr, 4096, 512, 192);

  for (int l=0; l<4; ++l){
    k_ln<<<dim3(1024), dim3(256), 0, stream>>>(h, ln1_w + l*512, ln1_b + l*512, xn);
    k_gemm<128, EPI_BF16><<<dim3(32,12), 256, 0, stream>>>(
        xn, inpwB + (size_t)l*1536*512, inp_b + l*1536, nullptr, qkv, 4096, 1536, 512);
    k_attn<<<dim3(32,8,2), 256, 0, stream>>>(qkv, ob);
    k_gemm<128, EPI_F32RES><<<dim3(32,4), 256, 0, stream>>>(
        ob, outpwB + (size_t)l*512*512, outp_b + l*512, h, nullptr, 4096, 512, 512);
    k_ln<<<dim3(1024), dim3(256), 0, stream>>>(h, ln2_w + l*512, ln2_b + l*512, xn);
    k_gemm<128, EPI_GELU><<<dim3(32,16), 256, 0, stream>>>(
        xn, w1B + (size_t)l*2048*512, b1 + l*2048, nullptr, a1, 4096, 2048, 512);
    k_gemm<128, EPI_F32RES><<<dim3(32,4), 256, 0, stream>>>(
        a1, w2B + (size_t)l*512*2048, b2 + l*512, h, nullptr, 4096, 512, 2048);
  }

  k_ln<<<dim3(1024), dim3(256), 0, stream>>>(h, fln_w, fln_b, xn);
  k_gemm<64, EPI_F32><<<dim3(32,3), 256, 0, stream>>>(
      xn, woutB, b_out, (float*)d_out, nullptr, 4096, 192, 512);
}

// Round 2
// 851.595 us; speedup vs baseline: 1.2657x; 1.2657x over previous
//
#include <hip/hip_runtime.h>
#include <hip/hip_bf16.h>
#include <math.h>

typedef short v8s __attribute__((ext_vector_type(8)));
typedef float v4f __attribute__((ext_vector_type(4)));
typedef unsigned int v4u __attribute__((ext_vector_type(4)));
typedef __hip_bfloat16 bf16;

__device__ inline short f2b(float f){
  __hip_bfloat16 h = __float2bfloat16(f);
  return __builtin_bit_cast(short, h);
}
__device__ inline unsigned int pack2(float x, float y){
  return ((unsigned int)(unsigned short)f2b(x)) |
         (((unsigned int)(unsigned short)f2b(y)) << 16);
}
__device__ inline v4f v4f_zero(){ v4f z = {0.f,0.f,0.f,0.f}; return z; }

__device__ inline void gload_lds16(const void* g, void* l){
  __builtin_amdgcn_global_load_lds(
      (__attribute__((address_space(1))) void*)(g),
      (__attribute__((address_space(3))) void*)(l), 16, 0, 0);
}

// ---------------- fp32 -> bf16 convert ----------------
__global__ __launch_bounds__(256) void k_cvt(const float* __restrict__ in,
                                             bf16* __restrict__ out, int n4){
  int i = blockIdx.x*256 + threadIdx.x;
  const int stride = gridDim.x*256;
  for (; i < n4; i += stride){
    float4 v = ((const float4*)in)[i];
    short4 o;
    o.x = f2b(v.x); o.y = f2b(v.y); o.z = f2b(v.z); o.w = f2b(v.w);
    ((short4*)out)[i] = o;
  }
}

// ---------------- LayerNorm: one wave per row of 512, fp32 in -> bf16 out ----------------
__global__ __launch_bounds__(256) void k_ln(const float* __restrict__ x,
                                            const float* __restrict__ w,
                                            const float* __restrict__ b,
                                            bf16* __restrict__ out){
  const int row  = blockIdx.x*4 + (threadIdx.x>>6);
  const int lane = threadIdx.x & 63;
  const float* xr = x + (size_t)row*512 + lane*8;
  float4 a = *(const float4*)xr;
  float4 c = *(const float4*)(xr+4);
  float s  = a.x+a.y+a.z+a.w + c.x+c.y+c.z+c.w;
  float sq = a.x*a.x+a.y*a.y+a.z*a.z+a.w*a.w + c.x*c.x+c.y*c.y+c.z*c.z+c.w*c.w;
  #pragma unroll
  for (int m=1;m<64;m<<=1){ s += __shfl_xor(s,m); sq += __shfl_xor(sq,m); }
  const float mean = s*(1.f/512.f);
  const float rstd = rsqrtf(sq*(1.f/512.f) - mean*mean + 1e-5f);
  const float* wp = w + lane*8; const float* bp = b + lane*8;
  float4 w0 = *(const float4*)wp, w1v = *(const float4*)(wp+4);
  float4 b0 = *(const float4*)bp, b1v = *(const float4*)(bp+4);
  v8s o;
  o[0]=f2b((a.x-mean)*rstd*w0.x +b0.x);
  o[1]=f2b((a.y-mean)*rstd*w0.y +b0.y);
  o[2]=f2b((a.z-mean)*rstd*w0.z +b0.z);
  o[3]=f2b((a.w-mean)*rstd*w0.w +b0.w);
  o[4]=f2b((c.x-mean)*rstd*w1v.x+b1v.x);
  o[5]=f2b((c.y-mean)*rstd*w1v.y+b1v.y);
  o[6]=f2b((c.z-mean)*rstd*w1v.z+b1v.z);
  o[7]=f2b((c.w-mean)*rstd*w1v.w+b1v.w);
  *(v8s*)(out + (size_t)row*512 + lane*8) = o;
}

// ---------------- GEMM: C[M,N] = A[M,K] * W[N,K]^T + bias, fused epilogues ----------------
enum { EPI_F32=0, EPI_BF16=1, EPI_F32RES=2, EPI_GELU=3, EPI_VT=4 };

template<int BN, int EPI>
__global__ __launch_bounds__(256) void k_gemm(
    const bf16* __restrict__ A, const bf16* __restrict__ W,
    const float* __restrict__ bias,
    float* __restrict__ resf, bf16* __restrict__ outb,
    const int M, const int N, const int K)
{
  constexpr int BM = 128;
  constexpr int FN = BN/32;
  __shared__ __align__(16) bf16 As[2][BM*32];
  __shared__ __align__(16) bf16 Bs[2][BN*32];
  const int tid  = threadIdx.x;
  const int wave = tid>>6, lane = tid&63;
  const int r = lane&15, g = lane>>4;
  const int bm = blockIdx.x*BM, bn = blockIdx.y*BN;
  const int wr = wave>>1, wc = wave&1;

  v4f acc[4][FN];
  #pragma unroll
  for (int i=0;i<4;++i)
    #pragma unroll
    for (int j=0;j<FN;++j) acc[i][j] = v4f_zero();

  const int NT = K >> 5;

  auto stage = [&](int buf, int kb){
    #pragma unroll
    for (int it=0; it<BM/64; ++it){
      const int cb = it*256 + wave*64;
      const int cc = cb + lane;
      const bf16* gp = A + (size_t)(bm + (cc>>2))*K + kb + (cc&3)*8;
      gload_lds16(gp, &As[buf][cb*8]);
    }
    #pragma unroll
    for (int it=0; it<BN/64; ++it){
      const int cb = it*256 + wave*64;
      const int cc = cb + lane;
      const bf16* gp = W + (size_t)(bn + (cc>>2))*K + kb + (cc&3)*8;
      gload_lds16(gp, &Bs[buf][cb*8]);
    }
  };

  stage(0, 0);
  int cur = 0;
  for (int t=0; t<NT; ++t){
    __syncthreads();
    if (t+1 < NT) stage(cur^1, (t+1)*32);
    const bf16* ap = &As[cur][(wr*64 + r)*32 + g*8];
    const bf16* bp = &Bs[cur][(wc*(BN/2) + r)*32 + g*8];
    v8s af[4], bfr[FN];
    #pragma unroll
    for (int i=0;i<4;++i) af[i] = *(const v8s*)(ap + i*16*32);
    #pragma unroll
    for (int j=0;j<FN;++j) bfr[j] = *(const v8s*)(bp + j*16*32);
    #pragma unroll
    for (int i=0;i<4;++i)
      #pragma unroll
      for (int j=0;j<FN;++j)
        acc[i][j] = __builtin_amdgcn_mfma_f32_16x16x32_bf16(af[i], bfr[j], acc[i][j], 0,0,0);
    cur ^= 1;
  }

  #pragma unroll
  for (int j=0;j<FN;++j){
    const int col = bn + wc*(BN/2) + j*16 + r;
    const float bv = bias[col];
    #pragma unroll
    for (int i=0;i<4;++i){
      const int row0 = bm + wr*64 + i*16 + g*4;
      if constexpr (EPI==EPI_VT){
        // col = h*64+d of V; rows are b*2048+s; write Vt[b][h][d][s], 4 s at once
        bf16* vt = outb + (((size_t)(row0>>11)*8 + (col>>6))*64 + (col&63))*2048 + (row0&2047);
        short4 st;
        st.x = f2b(acc[i][j][0] + bv);
        st.y = f2b(acc[i][j][1] + bv);
        st.z = f2b(acc[i][j][2] + bv);
        st.w = f2b(acc[i][j][3] + bv);
        *(short4*)vt = st;
      } else {
        #pragma unroll
        for (int q=0;q<4;++q){
          float v = acc[i][j][q] + bv;
          const size_t idx = (size_t)(row0+q)*N + col;
          if constexpr (EPI==EPI_F32)         resf[idx] = v;
          else if constexpr (EPI==EPI_F32RES) resf[idx] += v;
          else if constexpr (EPI==EPI_BF16)   outb[idx] = __float2bfloat16(v);
          else if constexpr (EPI==EPI_GELU){
            float gv = 0.5f*v*(1.f + erff(v*0.70710678118654752f));
            outb[idx] = __float2bfloat16(gv);
          }
        }
      }
    }
  }
}

// ---------------- causal + ALiBi flash attention, no LDS, no barriers ----------------
// qk: [B,S,1024] (Q cols 0..511, K cols 512..1023, per-head 64)
// vt: [B,NH,64,S] transposed V
// o : [B,S,512]
// grid (16, NH, B), block 256. Wave i handles 16-row q-tiles (4x+i) and (127-4x-i):
// exactly 65 k-tiles of 32 per wave -> perfect balance.
__global__ __launch_bounds__(256) void k_attn(const bf16* __restrict__ qk,
                                              const bf16* __restrict__ vt,
                                              bf16* __restrict__ o){
  const int x     = blockIdx.x;
  const int head  = blockIdx.y;
  const int batch = blockIdx.z;
  const int wave = threadIdx.x>>6, lane = threadIdx.x&63;
  const int r = lane&15, g = lane>>4;
  const float scale = 0.125f;
  const float slope = exp2f(-(float)(head+1));
  const bf16* qbase = qk + (size_t)batch*2048*1024 + head*64;
  const bf16* kbase = qbase + 512;
  const bf16* vbase = vt + (size_t)(batch*8 + head)*64*2048;
  const int w0 = x*4 + wave;

  for (int half=0; half<2; ++half){
    const int w = half ? (127 - w0) : w0;
    const int qtile = w*16;
    const int q = qtile + r;                 // this lane's q-row
    const bf16* qrow = qbase + (size_t)q*1024;
    const v8s qf0 = *(const v8s*)(qrow + g*8);
    const v8s qf1 = *(const v8s*)(qrow + 32 + g*8);

    v4f oacc[4];
    #pragma unroll
    for (int nf=0;nf<4;++nf) oacc[nf] = v4f_zero();
    float m = -1e30f, l = 0.f;
    const int nt = (w>>1) + 1;

    for (int t=0; t<nt; ++t){
      const int k0 = t*32;
      // K A-fragments straight from global (L2-hot), contiguous 16B
      const bf16* krow = kbase + (size_t)(k0 + r)*1024 + g*8;
      const v8s kf00 = *(const v8s*)(krow);
      const v8s kf01 = *(const v8s*)(krow + 32);
      const v8s kf10 = *(const v8s*)(krow + (size_t)16*1024);
      const v8s kf11 = *(const v8s*)(krow + (size_t)16*1024 + 32);
      // swapped QK^T: D[16k x 16q]; lane holds k = g*4+j for its own q = r
      v4f s0 = v4f_zero(), s1 = v4f_zero();
      s0 = __builtin_amdgcn_mfma_f32_16x16x32_bf16(kf00, qf0, s0, 0,0,0);
      s0 = __builtin_amdgcn_mfma_f32_16x16x32_bf16(kf01, qf1, s0, 0,0,0);
      s1 = __builtin_amdgcn_mfma_f32_16x16x32_bf16(kf10, qf0, s1, 0,0,0);
      s1 = __builtin_amdgcn_mfma_f32_16x16x32_bf16(kf11, qf1, s1, 0,0,0);

      const int kb0 = k0 + g*4;
      float v[8];
      #pragma unroll
      for (int j=0;j<4;++j) v[j]   = s0[j]*scale - slope*(float)(q - (kb0+j));
      #pragma unroll
      for (int j=0;j<4;++j) v[4+j] = s1[j]*scale - slope*(float)(q - (kb0+16+j));
      if (t == nt-1){
        #pragma unroll
        for (int j=0;j<4;++j){
          if (kb0+j    > q) v[j]   = -1e30f;
          if (kb0+16+j > q) v[4+j] = -1e30f;
        }
      }
      // online softmax: per-lane row, reduce only across the 4 g-groups
      float mt = v[0];
      #pragma unroll
      for (int j=1;j<8;++j) mt = fmaxf(mt, v[j]);
      mt = fmaxf(mt, __shfl_xor(mt,16));
      mt = fmaxf(mt, __shfl_xor(mt,32));
      const float mnew  = fmaxf(m, mt);
      const float alpha = __expf(m - mnew);
      float p[8]; float ps = 0.f;
      #pragma unroll
      for (int j=0;j<8;++j){ p[j] = __expf(v[j]-mnew); ps += p[j]; }
      ps += __shfl_xor(ps,16); ps += __shfl_xor(ps,32);
      l = l*alpha + ps; m = mnew;
      #pragma unroll
      for (int nf=0;nf<4;++nf) oacc[nf] *= alpha;

      // redistribute P into mfma B-fragment layout (k = g*8+j at col q=r)
      const unsigned int a0 = pack2(p[0],p[1]), a1 = pack2(p[2],p[3]);
      const unsigned int b0 = pack2(p[4],p[5]), b1 = pack2(p[6],p[7]);
      const int srcA = r + 16*((2*g)&3);
      const int srcB = srcA + 16;
      const unsigned int xa0 = __shfl(a0, srcA), xb0 = __shfl(b0, srcA);
      const unsigned int xa1 = __shfl(a1, srcA), xb1 = __shfl(b1, srcA);
      const unsigned int ya0 = __shfl(a0, srcB), yb0 = __shfl(b0, srcB);
      const unsigned int ya1 = __shfl(a1, srcB), yb1 = __shfl(b1, srcB);
      v4u wv;
      const bool lo = (g < 2);
      wv[0] = lo ? xa0 : xb0;
      wv[1] = lo ? xa1 : xb1;
      wv[2] = lo ? ya0 : yb0;
      wv[3] = lo ? ya1 : yb1;
      const v8s pf = __builtin_bit_cast(v8s, wv);

      // PV: O^T[16d x 16q] += Vt-frag * P ; Vt fragments contiguous 16B
      const bf16* vrow = vbase + (size_t)r*2048 + k0 + g*8;
      #pragma unroll
      for (int nf=0;nf<4;++nf){
        const v8s vf = *(const v8s*)(vrow + (size_t)nf*16*2048);
        oacc[nf] = __builtin_amdgcn_mfma_f32_16x16x32_bf16(vf, pf, oacc[nf], 0,0,0);
      }
    }

    const float inv = 1.f/l;
    bf16* orow = o + ((size_t)batch*2048 + q)*512 + head*64 + g*4;
    #pragma unroll
    for (int nf=0;nf<4;++nf){
      short4 st;
      st.x = f2b(oacc[nf][0]*inv);
      st.y = f2b(oacc[nf][1]*inv);
      st.z = f2b(oacc[nf][2]*inv);
      st.w = f2b(oacc[nf][3]*inv);
      *(short4*)(orow + nf*16) = st;
    }
  }
}

// ---------------- orchestration ----------------
extern "C" void kernel_launch(void* const* d_in, const int* in_sizes, int n_in,
                              void* d_out, int out_size, void* d_ws, size_t ws_size,
                              hipStream_t stream)
{
  const float* x     = (const float*)d_in[0];
  const float* w_emb = (const float*)d_in[1];
  const float* b_emb = (const float*)d_in[2];
  const float* ln1_w = (const float*)d_in[3];
  const float* ln1_b = (const float*)d_in[4];
  const float* inp_w = (const float*)d_in[5];
  const float* inp_b = (const float*)d_in[6];
  const float* outp_w= (const float*)d_in[7];
  const float* outp_b= (const float*)d_in[8];
  const float* ln2_w = (const float*)d_in[9];
  const float* ln2_b = (const float*)d_in[10];
  const float* w1    = (const float*)d_in[11];
  const float* b1    = (const float*)d_in[12];
  const float* w2    = (const float*)d_in[13];
  const float* b2    = (const float*)d_in[14];
  const float* fln_w = (const float*)d_in[15];
  const float* fln_b = (const float*)d_in[16];
  const float* w_out = (const float*)d_in[17];
  const float* b_out = (const float*)d_in[18];

  char* wsp = (char*)d_ws;
  auto alloc = [&](size_t bytes){ void* p = (void*)wsp; wsp += (bytes + 255) & ~(size_t)255; return p; };
  float* h     = (float*)alloc(4096UL*512*4);
  bf16* xn     = (bf16*) alloc(4096UL*512*2);
  bf16* qkb    = (bf16*) alloc(4096UL*1024*2);
  bf16* vtb    = (bf16*) alloc(2UL*8*64*2048*2);
  bf16* ob     = (bf16*) alloc(4096UL*512*2);
  bf16* a1     = (bf16*) alloc(4096UL*2048*2);
  bf16* xbf    = (bf16*) alloc(4096UL*192*2);
  bf16* wembB  = (bf16*) alloc(512UL*192*2);
  bf16* inpwB  = (bf16*) alloc(4UL*1536*512*2);
  bf16* outpwB = (bf16*) alloc(4UL*512*512*2);
  bf16* w1B    = (bf16*) alloc(4UL*2048*512*2);
  bf16* w2B    = (bf16*) alloc(4UL*512*2048*2);
  bf16* woutB  = (bf16*) alloc(192UL*512*2);

  auto cvt = [&](const float* s, bf16* dst, size_t n){
    int n4 = (int)(n/4);
    int blocks = (n4 + 255)/256; if (blocks > 2048) blocks = 2048;
    k_cvt<<<dim3(blocks), dim3(256), 0, stream>>>(s, dst, n4);
  };
  cvt(x, xbf, 4096UL*192);
  cvt(w_emb, wembB, 512UL*192);
  cvt(inp_w, inpwB, 4UL*1536*512);
  cvt(outp_w, outpwB, 4UL*512*512);
  cvt(w1, w1B, 4UL*2048*512);
  cvt(w2, w2B, 4UL*512*2048);
  cvt(w_out, woutB, 192UL*512);

  // h = x @ w_emb.T + b_emb
  k_gemm<128, EPI_F32><<<dim3(32,4), 256, 0, stream>>>(xbf, wembB, b_emb, h, nullptr, 4096, 512, 192);

  for (int l=0; l<4; ++l){
    k_ln<<<dim3(1024), dim3(256), 0, stream>>>(h, ln1_w + l*512, ln1_b + l*512, xn);
    // QK projection (cols 0..1023 of qkv)
    k_gemm<128, EPI_BF16><<<dim3(32,8), 256, 0, stream>>>(
        xn, inpwB + (size_t)l*1536*512, inp_b + l*1536, nullptr, qkb, 4096, 1024, 512);
    // V projection, written transposed [B,NH,64,S]
    k_gemm<128, EPI_VT><<<dim3(32,4), 256, 0, stream>>>(
        xn, inpwB + (size_t)l*1536*512 + 1024UL*512, inp_b + l*1536 + 1024, nullptr, vtb, 4096, 512, 512);
    k_attn<<<dim3(16,8,2), 256, 0, stream>>>(qkb, vtb, ob);
    k_gemm<128, EPI_F32RES><<<dim3(32,4), 256, 0, stream>>>(
        ob, outpwB + (size_t)l*512*512, outp_b + l*512, h, nullptr, 4096, 512, 512);
    k_ln<<<dim3(1024), dim3(256), 0, stream>>>(h, ln2_w + l*512, ln2_b + l*512, xn);
    k_gemm<128, EPI_GELU><<<dim3(32,16), 256, 0, stream>>>(
        xn, w1B + (size_t)l*2048*512, b1 + l*2048, nullptr, a1, 4096, 2048, 512);
    k_gemm<128, EPI_F32RES><<<dim3(32,4), 256, 0, stream>>>(
        a1, w2B + (size_t)l*512*2048, b2 + l*512, h, nullptr, 4096, 512, 2048);
  }

  k_ln<<<dim3(1024), dim3(256), 0, stream>>>(h, fln_w, fln_b, xn);
  k_gemm<64, EPI_F32><<<dim3(32,3), 256, 0, stream>>>(
      xn, woutB, b_out, (float*)d_out, nullptr, 4096, 192, 512);
}

// Round 3
// 705.038 us; speedup vs baseline: 1.5288x; 1.2079x over previous
//
#include <hip/hip_runtime.h>
#include <hip/hip_bf16.h>
#include <math.h>

typedef short v8s __attribute__((ext_vector_type(8)));
typedef float v4f __attribute__((ext_vector_type(4)));
typedef unsigned int v4u __attribute__((ext_vector_type(4)));
typedef __hip_bfloat16 bf16;

__device__ inline short f2b(float f){
  __hip_bfloat16 h = __float2bfloat16(f);
  return __builtin_bit_cast(short, h);
}
__device__ inline unsigned int pack2(float x, float y){
  return ((unsigned int)(unsigned short)f2b(x)) |
         (((unsigned int)(unsigned short)f2b(y)) << 16);
}
__device__ inline v4f v4f_zero(){ v4f z = {0.f,0.f,0.f,0.f}; return z; }

__device__ inline void gload_lds16(const void* g, void* l){
  __builtin_amdgcn_global_load_lds(
      (__attribute__((address_space(1))) void*)(g),
      (__attribute__((address_space(3))) void*)(l), 16, 0, 0);
}

// ---------------- fp32 -> bf16 convert ----------------
__global__ __launch_bounds__(256) void k_cvt(const float* __restrict__ in,
                                             bf16* __restrict__ out, int n4){
  int i = blockIdx.x*256 + threadIdx.x;
  const int stride = gridDim.x*256;
  for (; i < n4; i += stride){
    float4 v = ((const float4*)in)[i];
    short4 o;
    o.x = f2b(v.x); o.y = f2b(v.y); o.z = f2b(v.z); o.w = f2b(v.w);
    ((short4*)out)[i] = o;
  }
}

// ---------------- LayerNorm: one wave per row of 512, fp32 in -> bf16 out ----------------
__global__ __launch_bounds__(256) void k_ln(const float* __restrict__ x,
                                            const float* __restrict__ w,
                                            const float* __restrict__ b,
                                            bf16* __restrict__ out){
  const int row  = blockIdx.x*4 + (threadIdx.x>>6);
  const int lane = threadIdx.x & 63;
  const float* xr = x + (size_t)row*512 + lane*8;
  float4 a = *(const float4*)xr;
  float4 c = *(const float4*)(xr+4);
  float s  = a.x+a.y+a.z+a.w + c.x+c.y+c.z+c.w;
  float sq = a.x*a.x+a.y*a.y+a.z*a.z+a.w*a.w + c.x*c.x+c.y*c.y+c.z*c.z+c.w*c.w;
  #pragma unroll
  for (int m=1;m<64;m<<=1){ s += __shfl_xor(s,m); sq += __shfl_xor(sq,m); }
  const float mean = s*(1.f/512.f);
  const float rstd = rsqrtf(sq*(1.f/512.f) - mean*mean + 1e-5f);
  const float* wp = w + lane*8; const float* bp = b + lane*8;
  float4 w0 = *(const float4*)wp, w1v = *(const float4*)(wp+4);
  float4 b0 = *(const float4*)bp, b1v = *(const float4*)(bp+4);
  v8s o;
  o[0]=f2b((a.x-mean)*rstd*w0.x +b0.x);
  o[1]=f2b((a.y-mean)*rstd*w0.y +b0.y);
  o[2]=f2b((a.z-mean)*rstd*w0.z +b0.z);
  o[3]=f2b((a.w-mean)*rstd*w0.w +b0.w);
  o[4]=f2b((c.x-mean)*rstd*w1v.x+b1v.x);
  o[5]=f2b((c.y-mean)*rstd*w1v.y+b1v.y);
  o[6]=f2b((c.z-mean)*rstd*w1v.z+b1v.z);
  o[7]=f2b((c.w-mean)*rstd*w1v.w+b1v.w);
  *(v8s*)(out + (size_t)row*512 + lane*8) = o;
}

// ---------------- GEMM: C[M,N] = A[M,K] * W[N,K]^T + bias, fused epilogues ----------------
enum { EPI_F32=0, EPI_BF16=1, EPI_F32RES=2, EPI_GELU=3, EPI_VT=4 };

template<int BM, int BN, int EPI>
__global__ __launch_bounds__(256) void k_gemm(
    const bf16* __restrict__ A, const bf16* __restrict__ W,
    const float* __restrict__ bias,
    float* __restrict__ resf, bf16* __restrict__ outb,
    const int M, const int N, const int K)
{
  constexpr int FM = BM/32;
  constexpr int FN = BN/32;
  __shared__ __align__(16) bf16 As[2][BM*32];
  __shared__ __align__(16) bf16 Bs[2][BN*32];
  const int tid  = threadIdx.x;
  const int wave = tid>>6, lane = tid&63;
  const int r = lane&15, g = lane>>4;
  const int bm = blockIdx.x*BM, bn = blockIdx.y*BN;
  const int wr = wave>>1, wc = wave&1;

  v4f acc[FM][FN];
  #pragma unroll
  for (int i=0;i<FM;++i)
    #pragma unroll
    for (int j=0;j<FN;++j) acc[i][j] = v4f_zero();

  const int NT = K >> 5;

  auto stage = [&](int buf, int kb){
    #pragma unroll
    for (int it=0; it<BM/64; ++it){
      const int cb = it*256 + wave*64;
      const int cc = cb + lane;
      const bf16* gp = A + (size_t)(bm + (cc>>2))*K + kb + (cc&3)*8;
      gload_lds16(gp, &As[buf][cb*8]);
    }
    #pragma unroll
    for (int it=0; it<BN/64; ++it){
      const int cb = it*256 + wave*64;
      const int cc = cb + lane;
      const bf16* gp = W + (size_t)(bn + (cc>>2))*K + kb + (cc&3)*8;
      gload_lds16(gp, &Bs[buf][cb*8]);
    }
  };

  stage(0, 0);
  int cur = 0;
  for (int t=0; t<NT; ++t){
    __syncthreads();
    if (t+1 < NT) stage(cur^1, (t+1)*32);
    const bf16* ap = &As[cur][(wr*(BM/2) + r)*32 + g*8];
    const bf16* bp = &Bs[cur][(wc*(BN/2) + r)*32 + g*8];
    v8s af[FM], bfr[FN];
    #pragma unroll
    for (int i=0;i<FM;++i) af[i] = *(const v8s*)(ap + i*16*32);
    #pragma unroll
    for (int j=0;j<FN;++j) bfr[j] = *(const v8s*)(bp + j*16*32);
    #pragma unroll
    for (int i=0;i<FM;++i)
      #pragma unroll
      for (int j=0;j<FN;++j)
        acc[i][j] = __builtin_amdgcn_mfma_f32_16x16x32_bf16(af[i], bfr[j], acc[i][j], 0,0,0);
    cur ^= 1;
  }

  #pragma unroll
  for (int j=0;j<FN;++j){
    const int col = bn + wc*(BN/2) + j*16 + r;
    const float bv = bias[col];
    #pragma unroll
    for (int i=0;i<FM;++i){
      const int row0 = bm + wr*(BM/2) + i*16 + g*4;
      if constexpr (EPI==EPI_VT){
        // col = h*64+d of V; rows are b*2048+s; write Vt[b][h][d][s], 4 s at once
        bf16* vt = outb + (((size_t)(row0>>11)*8 + (col>>6))*64 + (col&63))*2048 + (row0&2047);
        short4 st;
        st.x = f2b(acc[i][j][0] + bv);
        st.y = f2b(acc[i][j][1] + bv);
        st.z = f2b(acc[i][j][2] + bv);
        st.w = f2b(acc[i][j][3] + bv);
        *(short4*)vt = st;
      } else {
        #pragma unroll
        for (int q=0;q<4;++q){
          float v = acc[i][j][q] + bv;
          const size_t idx = (size_t)(row0+q)*N + col;
          if constexpr (EPI==EPI_F32)         resf[idx] = v;
          else if constexpr (EPI==EPI_F32RES) resf[idx] += v;
          else if constexpr (EPI==EPI_BF16)   outb[idx] = __float2bfloat16(v);
          else if constexpr (EPI==EPI_GELU){
            float gv = 0.5f*v*(1.f + erff(v*0.70710678118654752f));
            outb[idx] = __float2bfloat16(gv);
          }
        }
      }
    }
  }
}

// ---------------- causal + ALiBi flash attention, split-K across 4 waves ----------------
// qk: [B,S,1024] (Q cols 0..511, K cols 512..1023, per-head 64)
// vt: [B,NH,64,S] transposed V
// o : [B,S,512]
// grid (64, NH, B), block 256. Block = 32 q-rows (2 subtiles of 16);
// wave sp handles k-tiles t = sp, sp+4, ... ; partials merged in LDS.
__global__ __launch_bounds__(256) void k_attn(const bf16* __restrict__ qk,
                                              const bf16* __restrict__ vt,
                                              bf16* __restrict__ o){
  const int bx    = blockIdx.x;
  const int head  = blockIdx.y;
  const int batch = blockIdx.z;
  const int sp = threadIdx.x>>6, lane = threadIdx.x&63;
  const int r = lane&15, g = lane>>4;
  const float scale = 0.125f;
  const float slope = exp2f(-(float)(head+1));
  const bf16* qbase = qk + (size_t)batch*2048*1024 + head*64;
  const bf16* kbase = qbase + 512;
  const bf16* vbase = vt + (size_t)(batch*8 + head)*64*2048;
  const int qt0 = bx*32;
  const int nt  = bx + 1;          // k-tiles of 32 covering causal range

  __shared__ float Ms[4][2][16];
  __shared__ float Ls[4][2][16];
  __shared__ __align__(16) v4f Os[4][2][4][64];

  // Q fragments for both 16-row subtiles
  v8s qf[2][2];
  #pragma unroll
  for (int u=0;u<2;++u){
    const bf16* qrow = qbase + (size_t)(qt0 + u*16 + r)*1024 + g*8;
    qf[u][0] = *(const v8s*)qrow;
    qf[u][1] = *(const v8s*)(qrow + 32);
  }

  v4f oacc[2][4];
  #pragma unroll
  for (int u=0;u<2;++u)
    #pragma unroll
    for (int nf=0;nf<4;++nf) oacc[u][nf] = v4f_zero();
  float m[2] = {-1e30f,-1e30f}, l[2] = {0.f,0.f};

  for (int t=sp; t<nt; t+=4){
    const int k0 = t*32;
    // K A-fragments straight from global (L2-hot), contiguous 16B
    const bf16* krow = kbase + (size_t)(k0 + r)*1024 + g*8;
    const v8s kf00 = *(const v8s*)(krow);
    const v8s kf01 = *(const v8s*)(krow + 32);
    const v8s kf10 = *(const v8s*)(krow + (size_t)16*1024);
    const v8s kf11 = *(const v8s*)(krow + (size_t)16*1024 + 32);
    // V fragments (shared by both subtiles)
    const bf16* vrow = vbase + (size_t)r*2048 + k0 + g*8;
    v8s vf[4];
    #pragma unroll
    for (int nf=0;nf<4;++nf) vf[nf] = *(const v8s*)(vrow + (size_t)nf*16*2048);

    #pragma unroll
    for (int u=0;u<2;++u){
      const int q = qt0 + u*16 + r;
      // swapped QK^T: D[16k x 16q]; lane holds k = g*4+j for its own q = r
      v4f s0 = v4f_zero(), s1 = v4f_zero();
      s0 = __builtin_amdgcn_mfma_f32_16x16x32_bf16(kf00, qf[u][0], s0, 0,0,0);
      s0 = __builtin_amdgcn_mfma_f32_16x16x32_bf16(kf01, qf[u][1], s0, 0,0,0);
      s1 = __builtin_amdgcn_mfma_f32_16x16x32_bf16(kf10, qf[u][0], s1, 0,0,0);
      s1 = __builtin_amdgcn_mfma_f32_16x16x32_bf16(kf11, qf[u][1], s1, 0,0,0);

      const int kb0 = k0 + g*4;
      float v[8];
      #pragma unroll
      for (int j=0;j<4;++j) v[j]   = s0[j]*scale - slope*(float)(q - (kb0+j));
      #pragma unroll
      for (int j=0;j<4;++j) v[4+j] = s1[j]*scale - slope*(float)(q - (kb0+16+j));
      if (t == nt-1){
        #pragma unroll
        for (int j=0;j<4;++j){
          if (kb0+j    > q) v[j]   = -1e30f;
          if (kb0+16+j > q) v[4+j] = -1e30f;
        }
      }
      // online softmax: per-lane row, reduce only across the 4 g-groups
      float mt = v[0];
      #pragma unroll
      for (int j=1;j<8;++j) mt = fmaxf(mt, v[j]);
      mt = fmaxf(mt, __shfl_xor(mt,16));
      mt = fmaxf(mt, __shfl_xor(mt,32));
      const float mnew  = fmaxf(m[u], mt);
      const float alpha = __expf(m[u] - mnew);
      float p[8]; float ps = 0.f;
      #pragma unroll
      for (int j=0;j<8;++j){ p[j] = __expf(v[j]-mnew); ps += p[j]; }
      ps += __shfl_xor(ps,16); ps += __shfl_xor(ps,32);
      l[u] = l[u]*alpha + ps; m[u] = mnew;
      #pragma unroll
      for (int nf=0;nf<4;++nf) oacc[u][nf] *= alpha;

      // redistribute P into mfma B-fragment layout (k = g*8+j at col q=r)
      const unsigned int a0 = pack2(p[0],p[1]), a1 = pack2(p[2],p[3]);
      const unsigned int b0 = pack2(p[4],p[5]), b1 = pack2(p[6],p[7]);
      const int srcA = r + 16*((2*g)&3);
      const int srcB = srcA + 16;
      const unsigned int xa0 = __shfl(a0, srcA), xb0 = __shfl(b0, srcA);
      const unsigned int xa1 = __shfl(a1, srcA), xb1 = __shfl(b1, srcA);
      const unsigned int ya0 = __shfl(a0, srcB), yb0 = __shfl(b0, srcB);
      const unsigned int ya1 = __shfl(a1, srcB), yb1 = __shfl(b1, srcB);
      v4u wv;
      const bool lo = (g < 2);
      wv[0] = lo ? xa0 : xb0;
      wv[1] = lo ? xa1 : xb1;
      wv[2] = lo ? ya0 : yb0;
      wv[3] = lo ? ya1 : yb1;
      const v8s pf = __builtin_bit_cast(v8s, wv);

      // PV: O^T[16d x 16q] += Vt-frag * P
      #pragma unroll
      for (int nf=0;nf<4;++nf)
        oacc[u][nf] = __builtin_amdgcn_mfma_f32_16x16x32_bf16(vf[nf], pf, oacc[u][nf], 0,0,0);
    }
  }

  // write partials
  #pragma unroll
  for (int u=0;u<2;++u){
    if (g == 0){ Ms[sp][u][r] = m[u]; Ls[sp][u][r] = l[u]; }
    #pragma unroll
    for (int nf=0;nf<4;++nf) Os[sp][u][nf][lane] = oacc[u][nf];
  }
  __syncthreads();

  // merge: wave 0 -> subtile 0, wave 1 -> subtile 1
  if (sp < 2){
    const int u = sp;
    float M = -1e30f;
    #pragma unroll
    for (int ss=0;ss<4;++ss) M = fmaxf(M, Ms[ss][u][r]);
    float L = 0.f;
    v4f O[4];
    #pragma unroll
    for (int nf=0;nf<4;++nf) O[nf] = v4f_zero();
    #pragma unroll
    for (int ss=0;ss<4;++ss){
      const float w = __expf(Ms[ss][u][r] - M);
      L += w * Ls[ss][u][r];
      #pragma unroll
      for (int nf=0;nf<4;++nf) O[nf] += w * Os[ss][u][nf][lane];
    }
    const float inv = 1.f/L;
    const int q = qt0 + u*16 + r;
    bf16* orow = o + ((size_t)batch*2048 + q)*512 + head*64 + g*4;
    #pragma unroll
    for (int nf=0;nf<4;++nf){
      short4 st;
      st.x = f2b(O[nf][0]*inv);
      st.y = f2b(O[nf][1]*inv);
      st.z = f2b(O[nf][2]*inv);
      st.w = f2b(O[nf][3]*inv);
      *(short4*)(orow + nf*16) = st;
    }
  }
}

// ---------------- orchestration ----------------
extern "C" void kernel_launch(void* const* d_in, const int* in_sizes, int n_in,
                              void* d_out, int out_size, void* d_ws, size_t ws_size,
                              hipStream_t stream)
{
  const float* x     = (const float*)d_in[0];
  const float* w_emb = (const float*)d_in[1];
  const float* b_emb = (const float*)d_in[2];
  const float* ln1_w = (const float*)d_in[3];
  const float* ln1_b = (const float*)d_in[4];
  const float* inp_w = (const float*)d_in[5];
  const float* inp_b = (const float*)d_in[6];
  const float* outp_w= (const float*)d_in[7];
  const float* outp_b= (const float*)d_in[8];
  const float* ln2_w = (const float*)d_in[9];
  const float* ln2_b = (const float*)d_in[10];
  const float* w1    = (const float*)d_in[11];
  const float* b1    = (const float*)d_in[12];
  const float* w2    = (const float*)d_in[13];
  const float* b2    = (const float*)d_in[14];
  const float* fln_w = (const float*)d_in[15];
  const float* fln_b = (const float*)d_in[16];
  const float* w_out = (const float*)d_in[17];
  const float* b_out = (const float*)d_in[18];

  char* wsp = (char*)d_ws;
  auto alloc = [&](size_t bytes){ void* p = (void*)wsp; wsp += (bytes + 255) & ~(size_t)255; return p; };
  float* h     = (float*)alloc(4096UL*512*4);
  bf16* xn     = (bf16*) alloc(4096UL*512*2);
  bf16* qkb    = (bf16*) alloc(4096UL*1024*2);
  bf16* vtb    = (bf16*) alloc(2UL*8*64*2048*2);
  bf16* ob     = (bf16*) alloc(4096UL*512*2);
  bf16* a1     = (bf16*) alloc(4096UL*2048*2);
  bf16* xbf    = (bf16*) alloc(4096UL*192*2);
  bf16* wembB  = (bf16*) alloc(512UL*192*2);
  bf16* inpwB  = (bf16*) alloc(4UL*1536*512*2);
  bf16* outpwB = (bf16*) alloc(4UL*512*512*2);
  bf16* w1B    = (bf16*) alloc(4UL*2048*512*2);
  bf16* w2B    = (bf16*) alloc(4UL*512*2048*2);
  bf16* woutB  = (bf16*) alloc(192UL*512*2);

  auto cvt = [&](const float* s, bf16* dst, size_t n){
    int n4 = (int)(n/4);
    int blocks = (n4 + 255)/256; if (blocks > 2048) blocks = 2048;
    k_cvt<<<dim3(blocks), dim3(256), 0, stream>>>(s, dst, n4);
  };
  cvt(x, xbf, 4096UL*192);
  cvt(w_emb, wembB, 512UL*192);
  cvt(inp_w, inpwB, 4UL*1536*512);
  cvt(outp_w, outpwB, 4UL*512*512);
  cvt(w1, w1B, 4UL*2048*512);
  cvt(w2, w2B, 4UL*512*2048);
  cvt(w_out, woutB, 192UL*512);

  // h = x @ w_emb.T + b_emb
  k_gemm<64,128, EPI_F32><<<dim3(64,4), 256, 0, stream>>>(xbf, wembB, b_emb, h, nullptr, 4096, 512, 192);

  for (int l=0; l<4; ++l){
    k_ln<<<dim3(1024), dim3(256), 0, stream>>>(h, ln1_w + l*512, ln1_b + l*512, xn);
    // QK projection (cols 0..1023 of qkv)
    k_gemm<64,128, EPI_BF16><<<dim3(64,8), 256, 0, stream>>>(
        xn, inpwB + (size_t)l*1536*512, inp_b + l*1536, nullptr, qkb, 4096, 1024, 512);
    // V projection, written transposed [B,NH,64,S]
    k_gemm<64,128, EPI_VT><<<dim3(64,4), 256, 0, stream>>>(
        xn, inpwB + (size_t)l*1536*512 + 1024UL*512, inp_b + l*1536 + 1024, nullptr, vtb, 4096, 512, 512);
    k_attn<<<dim3(64,8,2), 256, 0, stream>>>(qkb, vtb, ob);
    k_gemm<64,128, EPI_F32RES><<<dim3(64,4), 256, 0, stream>>>(
        ob, outpwB + (size_t)l*512*512, outp_b + l*512, h, nullptr, 4096, 512, 512);
    k_ln<<<dim3(1024), dim3(256), 0, stream>>>(h, ln2_w + l*512, ln2_b + l*512, xn);
    k_gemm<64,128, EPI_GELU><<<dim3(64,16), 256, 0, stream>>>(
        xn, w1B + (size_t)l*2048*512, b1 + l*2048, nullptr, a1, 4096, 2048, 512);
    k_gemm<64,128, EPI_F32RES><<<dim3(64,4), 256, 0, stream>>>(
        a1, w2B + (size_t)l*512*2048, b2 + l*512, h, nullptr, 4096, 512, 2048);
  }

  k_ln<<<dim3(1024), dim3(256), 0, stream>>>(h, fln_w, fln_b, xn);
  k_gemm<64,64, EPI_F32><<<dim3(64,3), 256, 0, stream>>>(
      xn, woutB, b_out, (float*)d_out, nullptr, 4096, 192, 512);
}

// Round 4
// 702.858 us; speedup vs baseline: 1.5335x; 1.0031x over previous
//
#include <hip/hip_runtime.h>
#include <hip/hip_bf16.h>
#include <math.h>

typedef short v8s __attribute__((ext_vector_type(8)));
typedef float v4f __attribute__((ext_vector_type(4)));
typedef unsigned int v4u __attribute__((ext_vector_type(4)));
typedef __hip_bfloat16 bf16;

__device__ inline short f2b(float f){
  __hip_bfloat16 h = __float2bfloat16(f);
  return __builtin_bit_cast(short, h);
}
__device__ inline unsigned int pack2(float x, float y){
  return ((unsigned int)(unsigned short)f2b(x)) |
         (((unsigned int)(unsigned short)f2b(y)) << 16);
}
__device__ inline v4f v4f_zero(){ v4f z = {0.f,0.f,0.f,0.f}; return z; }

__device__ inline void gload_lds16(const void* g, void* l){
  __builtin_amdgcn_global_load_lds(
      (__attribute__((address_space(1))) void*)(g),
      (__attribute__((address_space(3))) void*)(l), 16, 0, 0);
}

// ---------------- fp32 -> bf16 convert ----------------
__global__ __launch_bounds__(256) void k_cvt(const float* __restrict__ in,
                                             bf16* __restrict__ out, int n4){
  int i = blockIdx.x*256 + threadIdx.x;
  const int stride = gridDim.x*256;
  for (; i < n4; i += stride){
    float4 v = ((const float4*)in)[i];
    short4 o;
    o.x = f2b(v.x); o.y = f2b(v.y); o.z = f2b(v.z); o.w = f2b(v.w);
    ((short4*)out)[i] = o;
  }
}

// ---------------- LayerNorm: one wave per row of 512, fp32 in -> bf16 out ----------------
__global__ __launch_bounds__(256) void k_ln(const float* __restrict__ x,
                                            const float* __restrict__ w,
                                            const float* __restrict__ b,
                                            bf16* __restrict__ out){
  const int row  = blockIdx.x*4 + (threadIdx.x>>6);
  const int lane = threadIdx.x & 63;
  const float* xr = x + (size_t)row*512 + lane*8;
  float4 a = *(const float4*)xr;
  float4 c = *(const float4*)(xr+4);
  float s  = a.x+a.y+a.z+a.w + c.x+c.y+c.z+c.w;
  float sq = a.x*a.x+a.y*a.y+a.z*a.z+a.w*a.w + c.x*c.x+c.y*c.y+c.z*c.z+c.w*c.w;
  #pragma unroll
  for (int m=1;m<64;m<<=1){ s += __shfl_xor(s,m); sq += __shfl_xor(sq,m); }
  const float mean = s*(1.f/512.f);
  const float rstd = rsqrtf(sq*(1.f/512.f) - mean*mean + 1e-5f);
  const float* wp = w + lane*8; const float* bp = b + lane*8;
  float4 w0 = *(const float4*)wp, w1v = *(const float4*)(wp+4);
  float4 b0 = *(const float4*)bp, b1v = *(const float4*)(bp+4);
  v8s o;
  o[0]=f2b((a.x-mean)*rstd*w0.x +b0.x);
  o[1]=f2b((a.y-mean)*rstd*w0.y +b0.y);
  o[2]=f2b((a.z-mean)*rstd*w0.z +b0.z);
  o[3]=f2b((a.w-mean)*rstd*w0.w +b0.w);
  o[4]=f2b((c.x-mean)*rstd*w1v.x+b1v.x);
  o[5]=f2b((c.y-mean)*rstd*w1v.y+b1v.y);
  o[6]=f2b((c.z-mean)*rstd*w1v.z+b1v.z);
  o[7]=f2b((c.w-mean)*rstd*w1v.w+b1v.w);
  *(v8s*)(out + (size_t)row*512 + lane*8) = o;
}

// ---------------- GEMM: C[M,N] = A[M,K] * W[N,K]^T + bias, fused epilogues ----------------
enum { EPI_F32=0, EPI_BF16=1, EPI_F32RES=2, EPI_GELU=3, EPI_VT=4 };

template<int BM, int BN, int EPI>
__global__ __launch_bounds__(256) void k_gemm(
    const bf16* __restrict__ A, const bf16* __restrict__ W,
    const float* __restrict__ bias,
    float* __restrict__ resf, bf16* __restrict__ outb,
    const int M, const int N, const int K)
{
  constexpr int FM = BM/32;
  constexpr int FN = BN/32;
  __shared__ __align__(16) bf16 As[2][BM*32];
  __shared__ __align__(16) bf16 Bs[2][BN*32];
  const int tid  = threadIdx.x;
  const int wave = tid>>6, lane = tid&63;
  const int r = lane&15, g = lane>>4;
  const int bm = blockIdx.x*BM, bn = blockIdx.y*BN;
  const int wr = wave>>1, wc = wave&1;

  v4f acc[FM][FN];
  #pragma unroll
  for (int i=0;i<FM;++i)
    #pragma unroll
    for (int j=0;j<FN;++j) acc[i][j] = v4f_zero();

  const int NT = K >> 5;

  auto stage = [&](int buf, int kb){
    #pragma unroll
    for (int it=0; it<BM/64; ++it){
      const int cb = it*256 + wave*64;
      const int cc = cb + lane;
      const bf16* gp = A + (size_t)(bm + (cc>>2))*K + kb + (cc&3)*8;
      gload_lds16(gp, &As[buf][cb*8]);
    }
    #pragma unroll
    for (int it=0; it<BN/64; ++it){
      const int cb = it*256 + wave*64;
      const int cc = cb + lane;
      const bf16* gp = W + (size_t)(bn + (cc>>2))*K + kb + (cc&3)*8;
      gload_lds16(gp, &Bs[buf][cb*8]);
    }
  };

  stage(0, 0);
  int cur = 0;
  for (int t=0; t<NT; ++t){
    __syncthreads();
    if (t+1 < NT) stage(cur^1, (t+1)*32);
    const bf16* ap = &As[cur][(wr*(BM/2) + r)*32 + g*8];
    const bf16* bp = &Bs[cur][(wc*(BN/2) + r)*32 + g*8];
    v8s af[FM], bfr[FN];
    #pragma unroll
    for (int i=0;i<FM;++i) af[i] = *(const v8s*)(ap + i*16*32);
    #pragma unroll
    for (int j=0;j<FN;++j) bfr[j] = *(const v8s*)(bp + j*16*32);
    #pragma unroll
    for (int i=0;i<FM;++i)
      #pragma unroll
      for (int j=0;j<FN;++j)
        acc[i][j] = __builtin_amdgcn_mfma_f32_16x16x32_bf16(af[i], bfr[j], acc[i][j], 0,0,0);
    cur ^= 1;
  }

  #pragma unroll
  for (int j=0;j<FN;++j){
    const int col = bn + wc*(BN/2) + j*16 + r;
    const float bv = bias[col];
    #pragma unroll
    for (int i=0;i<FM;++i){
      const int row0 = bm + wr*(BM/2) + i*16 + g*4;
      if constexpr (EPI==EPI_VT){
        // col = h*64+d of V; rows are b*2048+s; write Vt[b][h][d][s], 4 s at once
        bf16* vt = outb + (((size_t)(row0>>11)*8 + (col>>6))*64 + (col&63))*2048 + (row0&2047);
        short4 st;
        st.x = f2b(acc[i][j][0] + bv);
        st.y = f2b(acc[i][j][1] + bv);
        st.z = f2b(acc[i][j][2] + bv);
        st.w = f2b(acc[i][j][3] + bv);
        *(short4*)vt = st;
      } else {
        #pragma unroll
        for (int q=0;q<4;++q){
          float v = acc[i][j][q] + bv;
          const size_t idx = (size_t)(row0+q)*N + col;
          if constexpr (EPI==EPI_F32)         resf[idx] = v;
          else if constexpr (EPI==EPI_F32RES) resf[idx] += v;
          else if constexpr (EPI==EPI_BF16)   outb[idx] = __float2bfloat16(v);
          else if constexpr (EPI==EPI_GELU){
            float gv = 0.5f*v*(1.f + erff(v*0.70710678118654752f));
            outb[idx] = __float2bfloat16(gv);
          }
        }
      }
    }
  }
}

// ---------------- causal + ALiBi flash attention ----------------
// qk: [B,S,1024] (Q cols 0..511, K cols 512..1023, per-head 64)
// vt: [B,NH,64,S] transposed V
// o : [B,S,512]
// grid (64, NH, B), block 256. Block = q-tile PAIR (bx, 127-bx): causal k-units
// sum to exactly 65 per block -> uniform work. Within each q-tile, wave sp takes
// k-tiles t = sp, sp+4, ...; partials merged in LDS at the end.
__global__ __launch_bounds__(256) void k_attn(const bf16* __restrict__ qk,
                                              const bf16* __restrict__ vt,
                                              bf16* __restrict__ o){
  const int bx    = blockIdx.x;
  const int head  = blockIdx.y;
  const int batch = blockIdx.z;
  const int sp = threadIdx.x>>6, lane = threadIdx.x&63;
  const int r = lane&15, g = lane>>4;
  const float scale = 0.125f;
  const float slope = exp2f(-(float)(head+1));
  const bf16* qbase = qk + (size_t)batch*2048*1024 + head*64;
  const bf16* kbase = qbase + 512;
  const bf16* vbase = vt + (size_t)(batch*8 + head)*64*2048;

  __shared__ float Ms[4][2][16];
  __shared__ float Ls[4][2][16];
  __shared__ __align__(16) v4f Os[4][2][4][64];

  const int wu0 = bx, wu1 = 127-bx;

  v4f oacc[2][4];
  #pragma unroll
  for (int u=0;u<2;++u)
    #pragma unroll
    for (int nf=0;nf<4;++nf) oacc[u][nf] = v4f_zero();
  float m[2] = {-1e30f,-1e30f}, l[2] = {0.f,0.f};

  #pragma unroll
  for (int u=0;u<2;++u){
    const int w = u ? wu1 : wu0;
    const int q = w*16 + r;                  // this lane's q-row
    const bf16* qrow = qbase + (size_t)q*1024 + g*8;
    const v8s qf0 = *(const v8s*)qrow;
    const v8s qf1 = *(const v8s*)(qrow + 32);
    const int nt = (w>>1) + 1;

    for (int t=sp; t<nt; t+=4){
      const int k0 = t*32;
      // K A-fragments straight from global (L2-hot), contiguous 16B
      const bf16* krow = kbase + (size_t)(k0 + r)*1024 + g*8;
      const v8s kf00 = *(const v8s*)(krow);
      const v8s kf01 = *(const v8s*)(krow + 32);
      const v8s kf10 = *(const v8s*)(krow + (size_t)16*1024);
      const v8s kf11 = *(const v8s*)(krow + (size_t)16*1024 + 32);
      // V fragments
      const bf16* vrow = vbase + (size_t)r*2048 + k0 + g*8;
      v8s vf[4];
      #pragma unroll
      for (int nf=0;nf<4;++nf) vf[nf] = *(const v8s*)(vrow + (size_t)nf*16*2048);

      // swapped QK^T: D[16k x 16q]; lane holds k = g*4+j for its own q = r
      v4f s0 = v4f_zero(), s1 = v4f_zero();
      s0 = __builtin_amdgcn_mfma_f32_16x16x32_bf16(kf00, qf0, s0, 0,0,0);
      s0 = __builtin_amdgcn_mfma_f32_16x16x32_bf16(kf01, qf1, s0, 0,0,0);
      s1 = __builtin_amdgcn_mfma_f32_16x16x32_bf16(kf10, qf0, s1, 0,0,0);
      s1 = __builtin_amdgcn_mfma_f32_16x16x32_bf16(kf11, qf1, s1, 0,0,0);

      const int kb0 = k0 + g*4;
      float v[8];
      #pragma unroll
      for (int j=0;j<4;++j) v[j]   = s0[j]*scale - slope*(float)(q - (kb0+j));
      #pragma unroll
      for (int j=0;j<4;++j) v[4+j] = s1[j]*scale - slope*(float)(q - (kb0+16+j));
      if (t == nt-1){
        #pragma unroll
        for (int j=0;j<4;++j){
          if (kb0+j    > q) v[j]   = -1e30f;
          if (kb0+16+j > q) v[4+j] = -1e30f;
        }
      }
      // online softmax: per-lane row, reduce only across the 4 g-groups
      float mt = v[0];
      #pragma unroll
      for (int j=1;j<8;++j) mt = fmaxf(mt, v[j]);
      mt = fmaxf(mt, __shfl_xor(mt,16));
      mt = fmaxf(mt, __shfl_xor(mt,32));
      const float mnew  = fmaxf(m[u], mt);
      const float alpha = __expf(m[u] - mnew);
      float p[8]; float ps = 0.f;
      #pragma unroll
      for (int j=0;j<8;++j){ p[j] = __expf(v[j]-mnew); ps += p[j]; }
      ps += __shfl_xor(ps,16); ps += __shfl_xor(ps,32);
      l[u] = l[u]*alpha + ps; m[u] = mnew;
      #pragma unroll
      for (int nf=0;nf<4;++nf) oacc[u][nf] *= alpha;

      // redistribute P into mfma B-fragment layout (k = g*8+j at col q=r)
      const unsigned int a0 = pack2(p[0],p[1]), a1 = pack2(p[2],p[3]);
      const unsigned int b0 = pack2(p[4],p[5]), b1 = pack2(p[6],p[7]);
      const int srcA = r + 16*((2*g)&3);
      const int srcB = srcA + 16;
      const unsigned int xa0 = __shfl(a0, srcA), xb0 = __shfl(b0, srcA);
      const unsigned int xa1 = __shfl(a1, srcA), xb1 = __shfl(b1, srcA);
      const unsigned int ya0 = __shfl(a0, srcB), yb0 = __shfl(b0, srcB);
      const unsigned int ya1 = __shfl(a1, srcB), yb1 = __shfl(b1, srcB);
      v4u wv;
      const bool lo = (g < 2);
      wv[0] = lo ? xa0 : xb0;
      wv[1] = lo ? xa1 : xb1;
      wv[2] = lo ? ya0 : yb0;
      wv[3] = lo ? ya1 : yb1;
      const v8s pf = __builtin_bit_cast(v8s, wv);

      // PV: O^T[16d x 16q] += Vt-frag * P
      #pragma unroll
      for (int nf=0;nf<4;++nf)
        oacc[u][nf] = __builtin_amdgcn_mfma_f32_16x16x32_bf16(vf[nf], pf, oacc[u][nf], 0,0,0);
    }
  }

  // write partials
  #pragma unroll
  for (int u=0;u<2;++u){
    if (g == 0){ Ms[sp][u][r] = m[u]; Ls[sp][u][r] = l[u]; }
    #pragma unroll
    for (int nf=0;nf<4;++nf) Os[sp][u][nf][lane] = oacc[u][nf];
  }
  __syncthreads();

  // merge: wave 0 -> subtile 0 (q-tile bx), wave 1 -> subtile 1 (q-tile 127-bx)
  if (sp < 2){
    const int u = sp;
    const int w = u ? wu1 : wu0;
    float M = -1e30f;
    #pragma unroll
    for (int ss=0;ss<4;++ss) M = fmaxf(M, Ms[ss][u][r]);
    float L = 0.f;
    v4f O[4];
    #pragma unroll
    for (int nf=0;nf<4;++nf) O[nf] = v4f_zero();
    #pragma unroll
    for (int ss=0;ss<4;++ss){
      const float wgt = __expf(Ms[ss][u][r] - M);
      L += wgt * Ls[ss][u][r];
      #pragma unroll
      for (int nf=0;nf<4;++nf) O[nf] += wgt * Os[ss][u][nf][lane];
    }
    const float inv = 1.f/L;
    const int q = w*16 + r;
    bf16* orow = o + ((size_t)batch*2048 + q)*512 + head*64 + g*4;
    #pragma unroll
    for (int nf=0;nf<4;++nf){
      short4 st;
      st.x = f2b(O[nf][0]*inv);
      st.y = f2b(O[nf][1]*inv);
      st.z = f2b(O[nf][2]*inv);
      st.w = f2b(O[nf][3]*inv);
      *(short4*)(orow + nf*16) = st;
    }
  }
}

// ---------------- orchestration ----------------
extern "C" void kernel_launch(void* const* d_in, const int* in_sizes, int n_in,
                              void* d_out, int out_size, void* d_ws, size_t ws_size,
                              hipStream_t stream)
{
  const float* x     = (const float*)d_in[0];
  const float* w_emb = (const float*)d_in[1];
  const float* b_emb = (const float*)d_in[2];
  const float* ln1_w = (const float*)d_in[3];
  const float* ln1_b = (const float*)d_in[4];
  const float* inp_w = (const float*)d_in[5];
  const float* inp_b = (const float*)d_in[6];
  const float* outp_w= (const float*)d_in[7];
  const float* outp_b= (const float*)d_in[8];
  const float* ln2_w = (const float*)d_in[9];
  const float* ln2_b = (const float*)d_in[10];
  const float* w1    = (const float*)d_in[11];
  const float* b1    = (const float*)d_in[12];
  const float* w2    = (const float*)d_in[13];
  const float* b2    = (const float*)d_in[14];
  const float* fln_w = (const float*)d_in[15];
  const float* fln_b = (const float*)d_in[16];
  const float* w_out = (const float*)d_in[17];
  const float* b_out = (const float*)d_in[18];

  char* wsp = (char*)d_ws;
  auto alloc = [&](size_t bytes){ void* p = (void*)wsp; wsp += (bytes + 255) & ~(size_t)255; return p; };
  float* h     = (float*)alloc(4096UL*512*4);
  bf16* xn     = (bf16*) alloc(4096UL*512*2);
  bf16* qkb    = (bf16*) alloc(4096UL*1024*2);
  bf16* vtb    = (bf16*) alloc(2UL*8*64*2048*2);
  bf16* ob     = (bf16*) alloc(4096UL*512*2);
  bf16* a1     = (bf16*) alloc(4096UL*2048*2);
  bf16* xbf    = (bf16*) alloc(4096UL*192*2);
  bf16* wembB  = (bf16*) alloc(512UL*192*2);
  bf16* inpwB  = (bf16*) alloc(4UL*1536*512*2);
  bf16* outpwB = (bf16*) alloc(4UL*512*512*2);
  bf16* w1B    = (bf16*) alloc(4UL*2048*512*2);
  bf16* w2B    = (bf16*) alloc(4UL*512*2048*2);
  bf16* woutB  = (bf16*) alloc(192UL*512*2);

  auto cvt = [&](const float* s, bf16* dst, size_t n){
    int n4 = (int)(n/4);
    int blocks = (n4 + 255)/256; if (blocks > 2048) blocks = 2048;
    k_cvt<<<dim3(blocks), dim3(256), 0, stream>>>(s, dst, n4);
  };
  cvt(x, xbf, 4096UL*192);
  cvt(w_emb, wembB, 512UL*192);
  cvt(inp_w, inpwB, 4UL*1536*512);
  cvt(outp_w, outpwB, 4UL*512*512);
  cvt(w1, w1B, 4UL*2048*512);
  cvt(w2, w2B, 4UL*512*2048);
  cvt(w_out, woutB, 192UL*512);

  // h = x @ w_emb.T + b_emb
  k_gemm<64,128, EPI_F32><<<dim3(64,4), 256, 0, stream>>>(xbf, wembB, b_emb, h, nullptr, 4096, 512, 192);

  for (int l=0; l<4; ++l){
    k_ln<<<dim3(1024), dim3(256), 0, stream>>>(h, ln1_w + l*512, ln1_b + l*512, xn);
    // QK projection (cols 0..1023 of qkv)
    k_gemm<64,128, EPI_BF16><<<dim3(64,8), 256, 0, stream>>>(
        xn, inpwB + (size_t)l*1536*512, inp_b + l*1536, nullptr, qkb, 4096, 1024, 512);
    // V projection, written transposed [B,NH,64,S]
    k_gemm<64,128, EPI_VT><<<dim3(64,4), 256, 0, stream>>>(
        xn, inpwB + (size_t)l*1536*512 + 1024UL*512, inp_b + l*1536 + 1024, nullptr, vtb, 4096, 512, 512);
    k_attn<<<dim3(64,8,2), 256, 0, stream>>>(qkb, vtb, ob);
    k_gemm<64,128, EPI_F32RES><<<dim3(64,4), 256, 0, stream>>>(
        ob, outpwB + (size_t)l*512*512, outp_b + l*512, h, nullptr, 4096, 512, 512);
    k_ln<<<dim3(1024), dim3(256), 0, stream>>>(h, ln2_w + l*512, ln2_b + l*512, xn);
    k_gemm<64,128, EPI_GELU><<<dim3(64,16), 256, 0, stream>>>(
        xn, w1B + (size_t)l*2048*512, b1 + l*2048, nullptr, a1, 4096, 2048, 512);
    k_gemm<64,128, EPI_F32RES><<<dim3(64,4), 256, 0, stream>>>(
        a1, w2B + (size_t)l*512*2048, b2 + l*512, h, nullptr, 4096, 512, 2048);
  }

  k_ln<<<dim3(1024), dim3(256), 0, stream>>>(h, fln_w, fln_b, xn);
  k_gemm<64,64, EPI_F32><<<dim3(64,3), 256, 0, stream>>>(
      xn, woutB, b_out, (float*)d_out, nullptr, 4096, 192, 512);
}

// Round 5
// 668.837 us; speedup vs baseline: 1.6115x; 1.0509x over previous
//
#include <hip/hip_runtime.h>
#include <hip/hip_bf16.h>
#include <math.h>

typedef short v8s __attribute__((ext_vector_type(8)));
typedef float v4f __attribute__((ext_vector_type(4)));
typedef unsigned int v2u __attribute__((ext_vector_type(2)));
typedef __hip_bfloat16 bf16;

__device__ inline short f2b(float f){
  __hip_bfloat16 h = __float2bfloat16(f);
  return __builtin_bit_cast(short, h);
}
__device__ inline unsigned int pack2(float x, float y){
  return ((unsigned int)(unsigned short)f2b(x)) |
         (((unsigned int)(unsigned short)f2b(y)) << 16);
}
__device__ inline v4f v4f_zero(){ v4f z = {0.f,0.f,0.f,0.f}; return z; }

__device__ inline void gload_lds16(const void* g, void* l){
  __builtin_amdgcn_global_load_lds(
      (__attribute__((address_space(1))) void*)(g),
      (__attribute__((address_space(3))) void*)(l), 16, 0, 0);
}

// ---------------- fp32 -> bf16 convert ----------------
__global__ __launch_bounds__(256) void k_cvt(const float* __restrict__ in,
                                             bf16* __restrict__ out, int n4){
  int i = blockIdx.x*256 + threadIdx.x;
  const int stride = gridDim.x*256;
  for (; i < n4; i += stride){
    float4 v = ((const float4*)in)[i];
    short4 o;
    o.x = f2b(v.x); o.y = f2b(v.y); o.z = f2b(v.z); o.w = f2b(v.w);
    ((short4*)out)[i] = o;
  }
}

// ---------------- LayerNorm: one wave per row of 512, fp32 in -> bf16 out ----------------
__global__ __launch_bounds__(256) void k_ln(const float* __restrict__ x,
                                            const float* __restrict__ w,
                                            const float* __restrict__ b,
                                            bf16* __restrict__ out){
  const int row  = blockIdx.x*4 + (threadIdx.x>>6);
  const int lane = threadIdx.x & 63;
  const float* xr = x + (size_t)row*512 + lane*8;
  float4 a = *(const float4*)xr;
  float4 c = *(const float4*)(xr+4);
  float s  = a.x+a.y+a.z+a.w + c.x+c.y+c.z+c.w;
  float sq = a.x*a.x+a.y*a.y+a.z*a.z+a.w*a.w + c.x*c.x+c.y*c.y+c.z*c.z+c.w*c.w;
  #pragma unroll
  for (int m=1;m<64;m<<=1){ s += __shfl_xor(s,m); sq += __shfl_xor(sq,m); }
  const float mean = s*(1.f/512.f);
  const float rstd = rsqrtf(sq*(1.f/512.f) - mean*mean + 1e-5f);
  const float* wp = w + lane*8; const float* bp = b + lane*8;
  float4 w0 = *(const float4*)wp, w1v = *(const float4*)(wp+4);
  float4 b0 = *(const float4*)bp, b1v = *(const float4*)(bp+4);
  v8s o;
  o[0]=f2b((a.x-mean)*rstd*w0.x +b0.x);
  o[1]=f2b((a.y-mean)*rstd*w0.y +b0.y);
  o[2]=f2b((a.z-mean)*rstd*w0.z +b0.z);
  o[3]=f2b((a.w-mean)*rstd*w0.w +b0.w);
  o[4]=f2b((c.x-mean)*rstd*w1v.x+b1v.x);
  o[5]=f2b((c.y-mean)*rstd*w1v.y+b1v.y);
  o[6]=f2b((c.z-mean)*rstd*w1v.z+b1v.z);
  o[7]=f2b((c.w-mean)*rstd*w1v.w+b1v.w);
  *(v8s*)(out + (size_t)row*512 + lane*8) = o;
}

// ---------------- GEMM: C[M,N] = A[M,K] * W[N,K]^T + bias, fused epilogues ----------------
enum { EPI_F32=0, EPI_BF16=1, EPI_F32RES=2, EPI_GELU=3, EPI_VT=4 };

template<int BM, int BN, int WR, int EPI>
__global__ __launch_bounds__(256) void k_gemm(
    const bf16* __restrict__ A, const bf16* __restrict__ W,
    const float* __restrict__ bias,
    float* __restrict__ resf, bf16* __restrict__ outb,
    const int M, const int N, const int K)
{
  constexpr int WC = 4/WR;
  constexpr int FM = BM/(WR*16);
  constexpr int FN = BN/(WC*16);
  __shared__ __align__(16) bf16 As[2][BM*32];
  __shared__ __align__(16) bf16 Bs[2][BN*32];
  const int tid  = threadIdx.x;
  const int wave = tid>>6, lane = tid&63;
  const int r = lane&15, g = lane>>4;
  const int bm = blockIdx.x*BM, bn = blockIdx.y*BN;
  const int wr = (WR==1) ? 0 : (wave>>1);
  const int wc = (WR==1) ? wave : (wave&1);

  v4f acc[FM][FN];
  #pragma unroll
  for (int i=0;i<FM;++i)
    #pragma unroll
    for (int j=0;j<FN;++j) acc[i][j] = v4f_zero();

  const int NT = K >> 5;

  auto stage = [&](int buf, int kb){
    constexpr int ACH = BM*4;   // 16B chunks in A-tile
    #pragma unroll
    for (int it=0; it<(ACH+255)/256; ++it){
      const int cb = it*256 + wave*64;
      if ((ACH & 255) == 0 || cb < ACH){
        const int cc = cb + lane;
        const bf16* gp = A + (size_t)(bm + (cc>>2))*K + kb + (cc&3)*8;
        gload_lds16(gp, &As[buf][cb*8]);
      }
    }
    constexpr int BCH = BN*4;
    #pragma unroll
    for (int it=0; it<(BCH+255)/256; ++it){
      const int cb = it*256 + wave*64;
      if ((BCH & 255) == 0 || cb < BCH){
        const int cc = cb + lane;
        const bf16* gp = W + (size_t)(bn + (cc>>2))*K + kb + (cc&3)*8;
        gload_lds16(gp, &Bs[buf][cb*8]);
      }
    }
  };

  stage(0, 0);
  int cur = 0;
  for (int t=0; t<NT; ++t){
    __syncthreads();
    if (t+1 < NT) stage(cur^1, (t+1)*32);
    const bf16* ap = &As[cur][(wr*(BM/WR) + r)*32 + g*8];
    const bf16* bp = &Bs[cur][(wc*(BN/WC) + r)*32 + g*8];
    v8s af[FM], bfr[FN];
    #pragma unroll
    for (int i=0;i<FM;++i) af[i] = *(const v8s*)(ap + i*16*32);
    #pragma unroll
    for (int j=0;j<FN;++j) bfr[j] = *(const v8s*)(bp + j*16*32);
    #pragma unroll
    for (int i=0;i<FM;++i)
      #pragma unroll
      for (int j=0;j<FN;++j)
        acc[i][j] = __builtin_amdgcn_mfma_f32_16x16x32_bf16(af[i], bfr[j], acc[i][j], 0,0,0);
    cur ^= 1;
  }

  #pragma unroll
  for (int j=0;j<FN;++j){
    const int col = bn + wc*(BN/WC) + j*16 + r;
    const float bv = bias[col];
    #pragma unroll
    for (int i=0;i<FM;++i){
      const int row0 = bm + wr*(BM/WR) + i*16 + g*4;
      if constexpr (EPI==EPI_VT){
        // col = h*64+d of V; rows are b*2048+s; write Vt[b][h][d][s], 4 s at once
        bf16* vt = outb + (((size_t)(row0>>11)*8 + (col>>6))*64 + (col&63))*2048 + (row0&2047);
        short4 st;
        st.x = f2b(acc[i][j][0] + bv);
        st.y = f2b(acc[i][j][1] + bv);
        st.z = f2b(acc[i][j][2] + bv);
        st.w = f2b(acc[i][j][3] + bv);
        *(short4*)vt = st;
      } else {
        #pragma unroll
        for (int q=0;q<4;++q){
          float v = acc[i][j][q] + bv;
          const size_t idx = (size_t)(row0+q)*N + col;
          if constexpr (EPI==EPI_F32)         resf[idx] = v;
          else if constexpr (EPI==EPI_F32RES) resf[idx] += v;
          else if constexpr (EPI==EPI_BF16)   outb[idx] = __float2bfloat16(v);
          else if constexpr (EPI==EPI_GELU){
            float gv = 0.5f*v*(1.f + erff(v*0.70710678118654752f));
            outb[idx] = __float2bfloat16(gv);
          }
        }
      }
    }
  }
}

// ---------------- causal + ALiBi flash attention ----------------
// qk: [B,S,1024] (Q cols 0..511, K cols 512..1023, per-head 64)
// vt: [B,NH,64,S] transposed V
// o : [B,S,512]
// grid (64, NH, B), block 256. Block = q-tile pair (bx, 127-bx); k-range of bx is
// a subset of 127-bx's, so one K/V fragment set serves both. Wave sp takes
// k-tiles t = sp, sp+4, ... (split-K), partials merged in LDS. K register-
// double-buffered; P transposed to mfma-B layout through padded wave-private LDS.
__global__ __launch_bounds__(256) void k_attn(const bf16* __restrict__ qk,
                                              const bf16* __restrict__ vt,
                                              bf16* __restrict__ o){
  const int bx    = blockIdx.x;
  const int head  = blockIdx.y;
  const int batch = blockIdx.z;
  const int sp = threadIdx.x>>6, lane = threadIdx.x&63;
  const int r = lane&15, g = lane>>4;
  const float LOG2E = 1.4426950408889634f;
  const float scale2 = 0.125f * LOG2E;
  const float slope2 = exp2f(-(float)(head+1)) * LOG2E;
  const bf16* qbase = qk + (size_t)batch*2048*1024 + head*64;
  const bf16* kbase = qbase + 512;
  const bf16* vbase = vt + (size_t)(batch*8 + head)*64*2048;

  __shared__ float Ms[4][2][16];
  __shared__ float Ls[4][2][16];
  __shared__ __align__(16) v4f Os[4][2][4][64];
  __shared__ __align__(16) short Psw[4][16][40];   // padded: row stride 80B

  const int w0 = bx, w1 = 127-bx;
  const int nt0 = (w0>>1) + 1;                     // <= 32
  const int nt1 = (w1>>1) + 1;                     // >= 33, nt0 <= nt1
  const int q0 = w0*16 + r, q1 = w1*16 + r;

  // Q fragments for both subtiles
  const bf16* q0p = qbase + (size_t)q0*1024 + g*8;
  const bf16* q1p = qbase + (size_t)q1*1024 + g*8;
  const v8s qf0A = *(const v8s*)q0p, qf0B = *(const v8s*)(q0p + 32);
  const v8s qf1A = *(const v8s*)q1p, qf1B = *(const v8s*)(q1p + 32);

  float cj[8];
  #pragma unroll
  for (int j=0;j<4;++j){ cj[j] = (float)j * slope2; cj[4+j] = (float)(16+j) * slope2; }

  v4f oacc0[4], oacc1[4];
  #pragma unroll
  for (int nf=0;nf<4;++nf){ oacc0[nf] = v4f_zero(); oacc1[nf] = v4f_zero(); }
  float m0 = -1e30f, l0 = 0.f, m1 = -1e30f, l1 = 0.f;

  v8s kf[4], kn[4], vf[4];
  auto loadK = [&](v8s* d, const bf16* kp){
    d[0] = *(const v8s*)(kp);
    d[1] = *(const v8s*)(kp + 32);
    d[2] = *(const v8s*)(kp + (size_t)16*1024);
    d[3] = *(const v8s*)(kp + (size_t)16*1024 + 32);
  };

  auto processU = [&](const v8s& qfA, const v8s& qfB, int dd, bool last,
                      float& m, float& l, v4f* oa){
    v4f s0 = v4f_zero(), s1 = v4f_zero();
    s0 = __builtin_amdgcn_mfma_f32_16x16x32_bf16(kf[0], qfA, s0, 0,0,0);
    s0 = __builtin_amdgcn_mfma_f32_16x16x32_bf16(kf[1], qfB, s0, 0,0,0);
    s1 = __builtin_amdgcn_mfma_f32_16x16x32_bf16(kf[2], qfA, s1, 0,0,0);
    s1 = __builtin_amdgcn_mfma_f32_16x16x32_bf16(kf[3], qfB, s1, 0,0,0);
    const float base = (float)dd * slope2;
    float v[8];
    #pragma unroll
    for (int j=0;j<4;++j) v[j]   = fmaf(s0[j], scale2, base + cj[j]);
    #pragma unroll
    for (int j=0;j<4;++j) v[4+j] = fmaf(s1[j], scale2, base + cj[4+j]);
    if (last){
      #pragma unroll
      for (int j=0;j<4;++j){
        if (dd + j      > 0) v[j]   = -1e30f;
        if (dd + 16 + j > 0) v[4+j] = -1e30f;
      }
    }
    float mt = v[0];
    #pragma unroll
    for (int j=1;j<8;++j) mt = fmaxf(mt, v[j]);
    mt = fmaxf(mt, __shfl_xor(mt,16));
    mt = fmaxf(mt, __shfl_xor(mt,32));
    const float mnew  = fmaxf(m, mt);
    const float alpha = exp2f(m - mnew);
    float p[8]; float ps = 0.f;
    #pragma unroll
    for (int j=0;j<8;++j){ p[j] = exp2f(v[j]-mnew); ps += p[j]; }
    ps += __shfl_xor(ps,16); ps += __shfl_xor(ps,32);
    l = l*alpha + ps; m = mnew;
    #pragma unroll
    for (int nf=0;nf<4;++nf) oa[nf] *= alpha;

    // P -> mfma B-fragment layout via padded wave-private LDS transpose
    v2u lo; lo[0] = pack2(p[0],p[1]); lo[1] = pack2(p[2],p[3]);
    v2u hi; hi[0] = pack2(p[4],p[5]); hi[1] = pack2(p[6],p[7]);
    *(v2u*)&Psw[sp][r][g*4]      = lo;   // k = g*4 .. g*4+3
    *(v2u*)&Psw[sp][r][16 + g*4] = hi;   // k = 16+g*4 ..
    const v8s pf = *(const v8s*)&Psw[sp][r][g*8];

    #pragma unroll
    for (int nf=0;nf<4;++nf)
      oa[nf] = __builtin_amdgcn_mfma_f32_16x16x32_bf16(vf[nf], pf, oa[nf], 0,0,0);
  };

  const bf16* kp = kbase + (size_t)(sp*32 + r)*1024 + g*8;
  const bf16* vp = vbase + (size_t)r*2048 + sp*32 + g*8;
  int dd0 = sp*32 + g*4 - q0;
  int dd1 = sp*32 + g*4 - q1;

  loadK(kf, kp);
  for (int t = sp; t < nt1; t += 4){
    #pragma unroll
    for (int nf=0;nf<4;++nf) vf[nf] = *(const v8s*)(vp + (size_t)nf*16*2048);
    const bool more = (t+4 < nt1);
    if (more) loadK(kn, kp + (size_t)4*32*1024);

    processU(qf1A, qf1B, dd1, t == nt1-1, m1, l1, oacc1);
    if (t < nt0)
      processU(qf0A, qf0B, dd0, t == nt0-1, m0, l0, oacc0);

    if (more){
      #pragma unroll
      for (int i=0;i<4;++i) kf[i] = kn[i];
      kp += (size_t)4*32*1024;
    }
    vp += 128; dd0 += 128; dd1 += 128;
  }

  // write partials (u=0 -> q-tile bx, u=1 -> q-tile 127-bx)
  if (g == 0){
    Ms[sp][0][r] = m0; Ls[sp][0][r] = l0;
    Ms[sp][1][r] = m1; Ls[sp][1][r] = l1;
  }
  #pragma unroll
  for (int nf=0;nf<4;++nf){ Os[sp][0][nf][lane] = oacc0[nf]; Os[sp][1][nf][lane] = oacc1[nf]; }
  __syncthreads();

  // merge: wave 0 -> u 0, wave 1 -> u 1
  if (sp < 2){
    const int u = sp;
    const int w = u ? w1 : w0;
    float M = -1e30f;
    #pragma unroll
    for (int ss=0;ss<4;++ss) M = fmaxf(M, Ms[ss][u][r]);
    float L = 0.f;
    v4f O[4];
    #pragma unroll
    for (int nf=0;nf<4;++nf) O[nf] = v4f_zero();
    #pragma unroll
    for (int ss=0;ss<4;++ss){
      const float wgt = exp2f(Ms[ss][u][r] - M);
      L += wgt * Ls[ss][u][r];
      #pragma unroll
      for (int nf=0;nf<4;++nf) O[nf] += wgt * Os[ss][u][nf][lane];
    }
    const float inv = 1.f/L;
    const int q = w*16 + r;
    bf16* orow = o + ((size_t)batch*2048 + q)*512 + head*64 + g*4;
    #pragma unroll
    for (int nf=0;nf<4;++nf){
      short4 st;
      st.x = f2b(O[nf][0]*inv);
      st.y = f2b(O[nf][1]*inv);
      st.z = f2b(O[nf][2]*inv);
      st.w = f2b(O[nf][3]*inv);
      *(short4*)(orow + nf*16) = st;
    }
  }
}

// ---------------- orchestration ----------------
extern "C" void kernel_launch(void* const* d_in, const int* in_sizes, int n_in,
                              void* d_out, int out_size, void* d_ws, size_t ws_size,
                              hipStream_t stream)
{
  const float* x     = (const float*)d_in[0];
  const float* w_emb = (const float*)d_in[1];
  const float* b_emb = (const float*)d_in[2];
  const float* ln1_w = (const float*)d_in[3];
  const float* ln1_b = (const float*)d_in[4];
  const float* inp_w = (const float*)d_in[5];
  const float* inp_b = (const float*)d_in[6];
  const float* outp_w= (const float*)d_in[7];
  const float* outp_b= (const float*)d_in[8];
  const float* ln2_w = (const float*)d_in[9];
  const float* ln2_b = (const float*)d_in[10];
  const float* w1    = (const float*)d_in[11];
  const float* b1    = (const float*)d_in[12];
  const float* w2    = (const float*)d_in[13];
  const float* b2    = (const float*)d_in[14];
  const float* fln_w = (const float*)d_in[15];
  const float* fln_b = (const float*)d_in[16];
  const float* w_out = (const float*)d_in[17];
  const float* b_out = (const float*)d_in[18];

  char* wsp = (char*)d_ws;
  auto alloc = [&](size_t bytes){ void* p = (void*)wsp; wsp += (bytes + 255) & ~(size_t)255; return p; };
  float* h     = (float*)alloc(4096UL*512*4);
  bf16* xn     = (bf16*) alloc(4096UL*512*2);
  bf16* qkb    = (bf16*) alloc(4096UL*1024*2);
  bf16* vtb    = (bf16*) alloc(2UL*8*64*2048*2);
  bf16* ob     = (bf16*) alloc(4096UL*512*2);
  bf16* a1     = (bf16*) alloc(4096UL*2048*2);
  bf16* xbf    = (bf16*) alloc(4096UL*192*2);
  bf16* wembB  = (bf16*) alloc(512UL*192*2);
  bf16* inpwB  = (bf16*) alloc(4UL*1536*512*2);
  bf16* outpwB = (bf16*) alloc(4UL*512*512*2);
  bf16* w1B    = (bf16*) alloc(4UL*2048*512*2);
  bf16* w2B    = (bf16*) alloc(4UL*512*2048*2);
  bf16* woutB  = (bf16*) alloc(192UL*512*2);

  auto cvt = [&](const float* s, bf16* dst, size_t n){
    int n4 = (int)(n/4);
    int blocks = (n4 + 255)/256; if (blocks > 2048) blocks = 2048;
    k_cvt<<<dim3(blocks), dim3(256), 0, stream>>>(s, dst, n4);
  };
  cvt(x, xbf, 4096UL*192);
  cvt(w_emb, wembB, 512UL*192);
  cvt(inp_w, inpwB, 4UL*1536*512);
  cvt(outp_w, outpwB, 4UL*512*512);
  cvt(w1, w1B, 4UL*2048*512);
  cvt(w2, w2B, 4UL*512*2048);
  cvt(w_out, woutB, 192UL*512);

  // h = x @ w_emb.T + b_emb
  k_gemm<32,128,1, EPI_F32><<<dim3(128,4), 256, 0, stream>>>(xbf, wembB, b_emb, h, nullptr, 4096, 512, 192);

  for (int l=0; l<4; ++l){
    k_ln<<<dim3(1024), dim3(256), 0, stream>>>(h, ln1_w + l*512, ln1_b + l*512, xn);
    // QK projection (cols 0..1023 of qkv)
    k_gemm<32,128,1, EPI_BF16><<<dim3(128,8), 256, 0, stream>>>(
        xn, inpwB + (size_t)l*1536*512, inp_b + l*1536, nullptr, qkb, 4096, 1024, 512);
    // V projection, written transposed [B,NH,64,S]
    k_gemm<32,128,1, EPI_VT><<<dim3(128,4), 256, 0, stream>>>(
        xn, inpwB + (size_t)l*1536*512 + 1024UL*512, inp_b + l*1536 + 1024, nullptr, vtb, 4096, 512, 512);
    k_attn<<<dim3(64,8,2), 256, 0, stream>>>(qkb, vtb, ob);
    k_gemm<32,128,1, EPI_F32RES><<<dim3(128,4), 256, 0, stream>>>(
        ob, outpwB + (size_t)l*512*512, outp_b + l*512, h, nullptr, 4096, 512, 512);
    k_ln<<<dim3(1024), dim3(256), 0, stream>>>(h, ln2_w + l*512, ln2_b + l*512, xn);
    k_gemm<64,128,2, EPI_GELU><<<dim3(64,16), 256, 0, stream>>>(
        xn, w1B + (size_t)l*2048*512, b1 + l*2048, nullptr, a1, 4096, 2048, 512);
    k_gemm<32,128,1, EPI_F32RES><<<dim3(128,4), 256, 0, stream>>>(
        a1, w2B + (size_t)l*512*2048, b2 + l*512, h, nullptr, 4096, 512, 2048);
  }

  k_ln<<<dim3(1024), dim3(256), 0, stream>>>(h, fln_w, fln_b, xn);
  k_gemm<32,64,1, EPI_F32><<<dim3(128,3), 256, 0, stream>>>(
      xn, woutB, b_out, (float*)d_out, nullptr, 4096, 192, 512);
}